// Round 8
// baseline (560.314 us; speedup 1.0000x reference)
//
#include <hip/hip_runtime.h>
#include <math.h>

#define BATCH 256
#define D0 256
#define D1 512
#define D2 256
#define D3 128

// fp32 inter-layer activations — replicating numpy's fp32 pipeline.
__device__ float g_xnT0[D0 * BATCH];
__device__ float g_xnT1[D1 * BATCH];
__device__ float g_xnT2[D2 * BATCH];

template <int L> __device__ __forceinline__ float* xnT_ptr() {
    if constexpr (L == 0) return g_xnT0;
    else if constexpr (L == 1) return g_xnT1;
    else return g_xnT2;
}

// Correctly-rounded fp32 exp via fp64 Taylor (trunc 2e-10 rel).
__device__ __forceinline__ float exp_f32_cr(float arg) {
    double t = (double)arg * 1.4426950408889634;   // log2(e)
    double n = rint(t);
    double f = t - n;                               // exact, |f|<=0.5
    double u = f * 0.6931471805599453;              // ln2, |u|<=0.347
    double p = 1.0 / 40320.0;
    p = fma(p, u, 1.0 / 5040.0);
    p = fma(p, u, 1.0 / 720.0);
    p = fma(p, u, 1.0 / 120.0);
    p = fma(p, u, 1.0 / 24.0);
    p = fma(p, u, 1.0 / 6.0);
    p = fma(p, u, 0.5);
    p = fma(p, u, 1.0);
    p = fma(p, u, 1.0);                             // e^u
    long long ni = (long long)n;                    // |n| small here
    double sc = __longlong_as_double((1023LL + ni) << 52);  // 2^n exact
    return (float)(p * sc);                         // single rounding to fp32
}

__device__ __forceinline__ float tanh_f32_cr(float x) {
    return (float)tanh((double)x);
}

__global__ void prep_tanhT(const float* __restrict__ x) {
    int i = threadIdx.x;   // 0..255
    int b = blockIdx.x;    // 0..255
    g_xnT0[i * BATCH + b] = tanh_f32_cr(x[b * D0 + i]);
}

// One wave per block: o = blockIdx.x (uniform weight rows -> s_loads),
// b = blockIdx.y*64 + lane (coalesced xn loads).
//
// EMULATES numpy einsum's float_sum_of_products_contig_contig_outstride0_two
// as actually compiled: einsum_sumprod.c.src is BASELINE-ONLY (not a
// .dispatch file) -> npyv = SSE (4 lanes), npyv_muladd = separate mul+add
// (no FMA in baseline), 4x unroll with reversed chain
//   ab3=p3+acc; ab2=p2+ab3; ab1=p1+ab2; acc=p0+ab1   (per lane, p=RN(a*b))
// over elements [pos+4j+l], then npyv_sum (SSE3 hadd x2): (v0+v1)+(v2+v3).
// K = IN*5 is a multiple of 16 -> no tail. Period lcm(16,5)=80 -> process
// 80-element super-blocks so (i, grid-idx) decompose at compile time.
template <int L, int IN, int OUT, bool FINAL>
__global__ __launch_bounds__(64) void kan_layer(
    const float* __restrict__ w, const float* __restrict__ s,
    const float* __restrict__ bias, float* __restrict__ outf)
{
#pragma clang fp contract(off)
    const int o = blockIdx.x;
    const int b = blockIdx.y * 64 + threadIdx.x;
    const float* __restrict__ xnT = xnT_ptr<L>();
    const float* __restrict__ wr = w + (size_t)o * IN * 5;
    const float* __restrict__ sr = s + (size_t)o * IN;
    constexpr int K = IN * 5;

    float vacc[4] = {0.f, 0.f, 0.f, 0.f};

#pragma unroll 1
    for (int blk = 0; blk < K; blk += 80) {
        const int ibase = blk / 5;                    // exact (blk % 5 == 0)
#pragma unroll
        for (int q = 0; q < 5; ++q) {                 // five 16-element groups
            float p[16];
#pragma unroll
            for (int t = 0; t < 16; ++t) {
                const int u = q * 16 + t;             // 0..79, compile-time
                const int i = ibase + u / 5;          // u/5 compile-time
                const int gi = u % 5;
                const float gv = 0.5f * (float)gi - 1.0f;   // exact grid pt
                const float xn = xnT[i * BATCH + b];  // CSE'd across same i
                const float sv = sr[i];               // uniform -> s_load
                const float d = fabsf(xn - gv);       // RN32, matches np
                const float e = exp_f32_cr(-(d * sv));
                p[t] = e * wr[blk + u];               // separate RN32 mul (contract off)
            }
#pragma unroll
            for (int l = 0; l < 4; ++l) {             // SSE lanes
                float a = vacc[l];
                a = p[12 + l] + a;                    // separate RN32 adds
                a = p[8 + l] + a;
                a = p[4 + l] + a;
                vacc[l] = p[0 + l] + a;
            }
        }
    }

    // npyv_sum_f32 (SSE3): hadd,hadd -> (v0+v1)+(v2+v3)
    float h = (vacc[0] + vacc[1]) + (vacc[2] + vacc[3]);
    h = h + bias[o];                                  // b == 0, exact

    if constexpr (FINAL) {
        outf[b * OUT + o] = tanh_f32_cr(h);
    } else {
        xnT_ptr<L + 1>()[o * BATCH + b] = tanh_f32_cr(fmaxf(h, 0.0f));
    }
}

extern "C" void kernel_launch(void* const* d_in, const int* in_sizes, int n_in,
                              void* d_out, int out_size, void* d_ws, size_t ws_size,
                              hipStream_t stream)
{
    const float* x  = (const float*)d_in[0];
    const float* w0 = (const float*)d_in[1];
    const float* s0 = (const float*)d_in[2];
    const float* b0 = (const float*)d_in[3];
    const float* w1 = (const float*)d_in[5];
    const float* s1 = (const float*)d_in[6];
    const float* b1 = (const float*)d_in[7];
    const float* w2 = (const float*)d_in[9];
    const float* s2 = (const float*)d_in[10];
    const float* b2 = (const float*)d_in[11];
    float* out = (float*)d_out;

    prep_tanhT<<<dim3(BATCH), dim3(D0), 0, stream>>>(x);

    kan_layer<0, D0, D1, false><<<dim3(D1, BATCH / 64), dim3(64), 0, stream>>>(w0, s0, b0, nullptr);
    kan_layer<1, D1, D2, false><<<dim3(D2, BATCH / 64), dim3(64), 0, stream>>>(w1, s1, b1, nullptr);
    kan_layer<2, D2, D3, true ><<<dim3(D3, BATCH / 64), dim3(64), 0, stream>>>(w2, s2, b2, out);
}

// Round 9
// 533.871 us; speedup vs baseline: 1.0495x; 1.0495x over previous
//
#include <hip/hip_runtime.h>
#include <math.h>

#define BATCH 256
#define D0 256
#define D1 512
#define D2 256
#define D3 128

// fp32 inter-layer activations — replicating numpy's fp32 pipeline.
__device__ float g_xnT0[D0 * BATCH];
__device__ float g_xnT1[D1 * BATCH];
__device__ float g_xnT2[D2 * BATCH];

template <int L> __device__ __forceinline__ float* xnT_ptr() {
    if constexpr (L == 0) return g_xnT0;
    else if constexpr (L == 1) return g_xnT1;
    else return g_xnT2;
}

// Correctly-rounded fp32 exp via fp64 Taylor (trunc 2e-10 rel).
// Tail uses ldexpf: RN32(p)*2^n == RN32(p*2^n) exactly (2^n scale exact,
// result >= e^-10 so no subnormals) — bit-identical to r8, fewer f64 ops.
__device__ __forceinline__ float exp_f32_cr(float arg) {
    double t = (double)arg * 1.4426950408889634;   // log2(e)
    double n = rint(t);
    double f = t - n;                               // exact, |f|<=0.5
    double u = f * 0.6931471805599453;              // ln2, |u|<=0.347
    double p = 1.0 / 40320.0;
    p = fma(p, u, 1.0 / 5040.0);
    p = fma(p, u, 1.0 / 720.0);
    p = fma(p, u, 1.0 / 120.0);
    p = fma(p, u, 1.0 / 24.0);
    p = fma(p, u, 1.0 / 6.0);
    p = fma(p, u, 0.5);
    p = fma(p, u, 1.0);
    p = fma(p, u, 1.0);                             // e^u, rel err 2e-10
    return ldexpf((float)p, (int)n);                // exact 2^n scale
}

__device__ __forceinline__ float tanh_f32_cr(float x) {
    return (float)tanh((double)x);
}

__global__ void prep_tanhT(const float* __restrict__ x) {
    int i = threadIdx.x;   // 0..255
    int b = blockIdx.x;    // 0..255
    g_xnT0[i * BATCH + b] = tanh_f32_cr(x[b * D0 + i]);
}

// One wave per block: o = blockIdx.x (uniform weight rows -> s_loads),
// b = blockIdx.y*64 + lane (coalesced xn loads).
//
// EMULATES numpy einsum's float_sum_of_products_contig_contig_outstride0_two
// as compiled in the wheel: baseline SSE (4 lanes), npyv_muladd = separate
// mul+add (no FMA), 4x unroll reversed chain
//   acc = p0 + (p4 + (p8 + (p12 + acc)))   per lane, p = RN32(a*b)
// then npyv_sum (SSE3 hadd x2): (v0+v1)+(v2+v3). K multiple of 16, no tail.
// lcm(16,5)=80 -> 80-element superblocks, indices decompose at compile time.
//
// PERF (r9): __launch_bounds__(64,2) lifts the VGPR cap 84->256 and
// unroll 2 gives ~160 independent fp64 exp chains per window — pure ILP;
// arithmetic and order are bit-identical to r8 (absmax must stay 0.01953125).
template <int L, int IN, int OUT, bool FINAL>
__global__ __launch_bounds__(64, 2) void kan_layer(
    const float* __restrict__ w, const float* __restrict__ s,
    const float* __restrict__ bias, float* __restrict__ outf)
{
#pragma clang fp contract(off)
    const int o = blockIdx.x;
    const int b = blockIdx.y * 64 + threadIdx.x;
    const float* __restrict__ xnT = xnT_ptr<L>();
    const float* __restrict__ wr = w + (size_t)o * IN * 5;
    const float* __restrict__ sr = s + (size_t)o * IN;
    constexpr int K = IN * 5;

    float vacc[4] = {0.f, 0.f, 0.f, 0.f};

#pragma unroll 2
    for (int blk = 0; blk < K; blk += 80) {
        const int ibase = blk / 5;                    // exact (blk % 5 == 0)
#pragma unroll
        for (int q = 0; q < 5; ++q) {                 // five 16-element groups
            float p[16];
#pragma unroll
            for (int t = 0; t < 16; ++t) {
                const int u = q * 16 + t;             // 0..79, compile-time
                const int i = ibase + u / 5;          // u/5 compile-time
                const int gi = u % 5;
                const float gv = 0.5f * (float)gi - 1.0f;   // exact grid pt
                const float xn = xnT[i * BATCH + b];  // CSE'd across same i
                const float sv = sr[i];               // uniform -> s_load
                const float d = fabsf(xn - gv);       // RN32, matches np
                const float e = exp_f32_cr(-(d * sv));
                p[t] = e * wr[blk + u];               // separate RN32 mul (contract off)
            }
#pragma unroll
            for (int l = 0; l < 4; ++l) {             // SSE lanes
                float a = vacc[l];
                a = p[12 + l] + a;                    // separate RN32 adds
                a = p[8 + l] + a;
                a = p[4 + l] + a;
                vacc[l] = p[0 + l] + a;
            }
        }
    }

    // npyv_sum_f32 (SSE3): hadd,hadd -> (v0+v1)+(v2+v3)
    float h = (vacc[0] + vacc[1]) + (vacc[2] + vacc[3]);
    h = h + bias[o];                                  // b == 0, exact

    if constexpr (FINAL) {
        outf[b * OUT + o] = tanh_f32_cr(h);
    } else {
        xnT_ptr<L + 1>()[o * BATCH + b] = tanh_f32_cr(fmaxf(h, 0.0f));
    }
}

extern "C" void kernel_launch(void* const* d_in, const int* in_sizes, int n_in,
                              void* d_out, int out_size, void* d_ws, size_t ws_size,
                              hipStream_t stream)
{
    const float* x  = (const float*)d_in[0];
    const float* w0 = (const float*)d_in[1];
    const float* s0 = (const float*)d_in[2];
    const float* b0 = (const float*)d_in[3];
    const float* w1 = (const float*)d_in[5];
    const float* s1 = (const float*)d_in[6];
    const float* b1 = (const float*)d_in[7];
    const float* w2 = (const float*)d_in[9];
    const float* s2 = (const float*)d_in[10];
    const float* b2 = (const float*)d_in[11];
    float* out = (float*)d_out;

    prep_tanhT<<<dim3(BATCH), dim3(D0), 0, stream>>>(x);

    kan_layer<0, D0, D1, false><<<dim3(D1, BATCH / 64), dim3(64), 0, stream>>>(w0, s0, b0, nullptr);
    kan_layer<1, D1, D2, false><<<dim3(D2, BATCH / 64), dim3(64), 0, stream>>>(w1, s1, b1, nullptr);
    kan_layer<2, D2, D3, true ><<<dim3(D3, BATCH / 64), dim3(64), 0, stream>>>(w2, s2, b2, out);
}

// Round 11
// 374.240 us; speedup vs baseline: 1.4972x; 1.4265x over previous
//
#include <hip/hip_runtime.h>
#include <math.h>

#define BATCH 256
#define D0 256
#define D1 512
#define D2 256
#define D3 128

// fp32 inter-layer activations — replicating numpy's fp32 pipeline.
__device__ float g_xnT0[D0 * BATCH];
__device__ float g_xnT1[D1 * BATCH];
__device__ float g_xnT2[D2 * BATCH];

template <int L> __device__ __forceinline__ float* xnT_ptr() {
    if constexpr (L == 0) return g_xnT0;
    else if constexpr (L == 1) return g_xnT1;
    else return g_xnT2;
}

__device__ __forceinline__ float tanh_f32_cr(float x) {
    return (float)tanh((double)x);
}

__global__ void prep_tanhT(const float* __restrict__ x) {
    int i = threadIdx.x;   // 0..255
    int b = blockIdx.x;    // 0..255
    g_xnT0[i * BATCH + b] = tanh_f32_cr(x[b * D0 + i]);
}

// One wave per block: o = blockIdx.x (uniform weight rows -> s_loads),
// b = blockIdx.y*64 + lane (coalesced xn loads).
//
// Numerics (DO NOT TOUCH — r8 passed at 1.95e-2 vs 2e-2 threshold): per-term
// fp32 ops d=|xn-g|, m=d*s; RN32(exp(m)) via fp64 deg-8 Taylor + exact ldexpf;
// product RN32 separate mul; accumulation = numpy einsum baseline-SSE
// emulation: 4 lanes, unfused mul+add, reversed chain
// acc = p0+(p4+(p8+(p12+acc))), hadd tree (v0+v1)+(v2+v3). K % 16 == 0.
//
// PERF (r11): r10's 16-wide SoA gave 534->364 us but spilled (live fp64 set
// ~200 VGPRs under the 256 cap) and post-timing diverged — spill-slot
// read-before-write signature (call 1 reads zeroed fresh scratch, later calls
// read dirty scratch). This round: 4 chunks x 4 parallel fp64 chains per SSE
// group — enough ILP to cover the ~8-12 cyc fp64 FMA latency (4 cyc issue),
// live set ~20 VGPRs per chunk, no spill. Op sequence and accumulation order
// bit-identical to r8/r9/r10.
template <int L, int IN, int OUT, bool FINAL>
__global__ __launch_bounds__(64, 2) void kan_layer(
    const float* __restrict__ w, const float* __restrict__ s,
    const float* __restrict__ bias, float* __restrict__ outf)
{
#pragma clang fp contract(off)
    const int o = blockIdx.x;
    const int b = blockIdx.y * 64 + threadIdx.x;
    const float* __restrict__ xnT = xnT_ptr<L>();
    const float* __restrict__ wr = w + (size_t)o * IN * 5;
    const float* __restrict__ sr = s + (size_t)o * IN;
    constexpr int K = IN * 5;

    float vacc[4] = {0.f, 0.f, 0.f, 0.f};

#pragma unroll 1
    for (int blk = 0; blk < K; blk += 80) {      // 80 = lcm(16,5): 16 i x 5 g
        const int ibase = blk / 5;
        float xnv[16];                            // activations for this superblock
#pragma unroll
        for (int ii = 0; ii < 16; ++ii)
            xnv[ii] = xnT[(ibase + ii) * BATCH + b];   // coalesced, L1/L2-hit

#pragma unroll
        for (int q = 0; q < 5; ++q) {                  // five 16-element SSE groups
            float p[16];
#pragma unroll
            for (int c = 0; c < 4; ++c) {              // 4 chunks x 4 parallel chains
                double uu[4], pp[4];
                int ni[4];
#pragma unroll
                for (int t = 0; t < 4; ++t) {          // args + range reduction
                    const int u = q * 16 + c * 4 + t;  // 0..79, compile-time
                    const int i = u / 5;
                    const int gi = u % 5;
                    const float gv = 0.5f * (float)gi - 1.0f;   // exact grid pt
                    const float d = fabsf(xnv[i] - gv);         // RN32
                    const float m = -(d * sr[ibase + i]);       // RN32, sv uniform
                    const double tt = (double)m * 1.4426950408889634;
                    const double nn = rint(tt);
                    ni[t] = (int)nn;
                    uu[t] = (tt - nn) * 0.6931471805599453;
                }
                // 4 independent fp64 Taylor chains, one step per unrolled block
#pragma unroll
                for (int t = 0; t < 4; ++t) pp[t] = fma(1.0 / 40320.0, uu[t], 1.0 / 5040.0);
#pragma unroll
                for (int t = 0; t < 4; ++t) pp[t] = fma(pp[t], uu[t], 1.0 / 720.0);
#pragma unroll
                for (int t = 0; t < 4; ++t) pp[t] = fma(pp[t], uu[t], 1.0 / 120.0);
#pragma unroll
                for (int t = 0; t < 4; ++t) pp[t] = fma(pp[t], uu[t], 1.0 / 24.0);
#pragma unroll
                for (int t = 0; t < 4; ++t) pp[t] = fma(pp[t], uu[t], 1.0 / 6.0);
#pragma unroll
                for (int t = 0; t < 4; ++t) pp[t] = fma(pp[t], uu[t], 0.5);
#pragma unroll
                for (int t = 0; t < 4; ++t) pp[t] = fma(pp[t], uu[t], 1.0);
#pragma unroll
                for (int t = 0; t < 4; ++t) pp[t] = fma(pp[t], uu[t], 1.0);
#pragma unroll
                for (int t = 0; t < 4; ++t)            // RN32, exact 2^n, RN32 mul
                    p[c * 4 + t] = ldexpf((float)pp[t], ni[t]) * wr[blk + q * 16 + c * 4 + t];
            }
            // SSE lane chains (order-locked)
#pragma unroll
            for (int l = 0; l < 4; ++l) {
                float a = vacc[l];
                a = p[12 + l] + a;
                a = p[8 + l] + a;
                a = p[4 + l] + a;
                vacc[l] = p[0 + l] + a;
            }
        }
    }

    // npyv_sum_f32 (SSE3): hadd,hadd -> (v0+v1)+(v2+v3)
    float h = (vacc[0] + vacc[1]) + (vacc[2] + vacc[3]);
    h = h + bias[o];                                  // b == 0, exact

    if constexpr (FINAL) {
        outf[b * OUT + o] = tanh_f32_cr(h);
    } else {
        xnT_ptr<L + 1>()[o * BATCH + b] = tanh_f32_cr(fmaxf(h, 0.0f));
    }
}

extern "C" void kernel_launch(void* const* d_in, const int* in_sizes, int n_in,
                              void* d_out, int out_size, void* d_ws, size_t ws_size,
                              hipStream_t stream)
{
    const float* x  = (const float*)d_in[0];
    const float* w0 = (const float*)d_in[1];
    const float* s0 = (const float*)d_in[2];
    const float* b0 = (const float*)d_in[3];
    const float* w1 = (const float*)d_in[5];
    const float* s1 = (const float*)d_in[6];
    const float* b1 = (const float*)d_in[7];
    const float* w2 = (const float*)d_in[9];
    const float* s2 = (const float*)d_in[10];
    const float* b2 = (const float*)d_in[11];
    float* out = (float*)d_out;

    prep_tanhT<<<dim3(BATCH), dim3(D0), 0, stream>>>(x);

    kan_layer<0, D0, D1, false><<<dim3(D1, BATCH / 64), dim3(64), 0, stream>>>(w0, s0, b0, nullptr);
    kan_layer<1, D1, D2, false><<<dim3(D2, BATCH / 64), dim3(64), 0, stream>>>(w1, s1, b1, nullptr);
    kan_layer<2, D2, D3, true ><<<dim3(D3, BATCH / 64), dim3(64), 0, stream>>>(w2, s2, b2, out);
}